// Round 1
// baseline (125.397 us; speedup 1.0000x reference)
//
#include <hip/hip_runtime.h>

typedef __bf16 bf16x8 __attribute__((ext_vector_type(8)));
typedef float f32x4 __attribute__((ext_vector_type(4)));
typedef unsigned short u16;
typedef u16 u16x8 __attribute__((ext_vector_type(8)));

#define LSEQ 2048
#define DMODEL 1024
#define HEADD 64
#define NBATCH 8

__device__ __forceinline__ u16 f2bf(float f) {
  union { float f; unsigned u; } v; v.f = f;
  unsigned r = v.u + 0x7FFFu + ((v.u >> 16) & 1u);
  return (u16)(r >> 16);
}

// ---------------------------------------------------------------------------
// Kernel 0: W [1024][64] fp32  ->  Wt [64][1024] bf16   (x3 weights)
// ---------------------------------------------------------------------------
__global__ void wt_kernel(const float* __restrict__ Wk, const float* __restrict__ Wq,
                          const float* __restrict__ Wv, u16* __restrict__ wt) {
  int n = blockIdx.x;   // head-dim column of W = row of Wt
  int p = blockIdx.y;   // which weight
  const float* W = (p == 0) ? Wk : ((p == 1) ? Wq : Wv);
  u16* dst = wt + ((size_t)p * HEADD + n) * DMODEL;
  for (int k = threadIdx.x; k < DMODEL; k += blockDim.x)
    dst[k] = f2bf(W[(size_t)k * HEADD + n]);
}

// ---------------------------------------------------------------------------
// Kernel 1: projections.  4 waves/block, wave owns 32 rows x 64 cols.
// A-frags read directly from global fp32 (lines fully consumed per k-step),
// B-frags are 16B contiguous bf16 loads from Wt (L2-resident).
// p==0 -> K row-major bf16 ; p==1 -> Q*0.125 row-major ; p==2 -> V^T [b][64][2048]
// ---------------------------------------------------------------------------
__global__ __launch_bounds__(256) void proj_kernel(
    const float* __restrict__ ik, const float* __restrict__ iq, const float* __restrict__ iv,
    const u16* __restrict__ wt, u16* __restrict__ Kb, u16* __restrict__ Qb,
    u16* __restrict__ Vt) {
  int p = blockIdx.y;
  const float* A = (p == 0) ? ik : ((p == 1) ? iq : iv);
  const u16* W = wt + (size_t)p * HEADD * DMODEL;
  int lane = threadIdx.x & 63;
  int wv = threadIdx.x >> 6;
  int l15 = lane & 15, g = lane >> 4;
  int rowbase = blockIdx.x * 128 + wv * 32;

  f32x4 acc[2][4] = {};  // [mf][c]: rows rowbase+16*mf+4g+r, cols 16c+l15
  for (int kk = 0; kk < DMODEL; kk += 32) {
    bf16x8 af[2];
#pragma unroll
    for (int mf = 0; mf < 2; ++mf) {
      const float* src = A + (size_t)(rowbase + mf * 16 + l15) * DMODEL + kk + 8 * g;
      float4 f0 = *(const float4*)src;
      float4 f1 = *(const float4*)(src + 4);
      u16x8 u;
      u[0] = f2bf(f0.x); u[1] = f2bf(f0.y); u[2] = f2bf(f0.z); u[3] = f2bf(f0.w);
      u[4] = f2bf(f1.x); u[5] = f2bf(f1.y); u[6] = f2bf(f1.z); u[7] = f2bf(f1.w);
      af[mf] = __builtin_bit_cast(bf16x8, u);
    }
#pragma unroll
    for (int c = 0; c < 4; ++c) {
      bf16x8 bfr = *(const bf16x8*)(W + (size_t)(16 * c + l15) * DMODEL + kk + 8 * g);
#pragma unroll
      for (int mf = 0; mf < 2; ++mf)
        acc[mf][c] = __builtin_amdgcn_mfma_f32_16x16x32_bf16(af[mf], bfr, acc[mf][c], 0, 0, 0);
    }
  }

  if (p == 2) {
    // store V transposed: Vt[b][d][tok], pack 4 consecutive tokens (r) -> 8B store
#pragma unroll
    for (int mf = 0; mf < 2; ++mf)
#pragma unroll
      for (int c = 0; c < 4; ++c) {
        int row0 = rowbase + mf * 16 + 4 * g;
        int b = row0 >> 11, tok = row0 & 2047;
        int d = 16 * c + l15;
        ushort4 pk;
        pk.x = f2bf(acc[mf][c][0]); pk.y = f2bf(acc[mf][c][1]);
        pk.z = f2bf(acc[mf][c][2]); pk.w = f2bf(acc[mf][c][3]);
        *(ushort4*)(Vt + ((size_t)b * HEADD + d) * LSEQ + tok) = pk;
      }
  } else {
    u16* dst = (p == 0) ? Kb : Qb;
    float s = (p == 1) ? 0.125f : 1.0f;  // fold softmax scale into Q (exact pow2)
#pragma unroll
    for (int mf = 0; mf < 2; ++mf)
#pragma unroll
      for (int c = 0; c < 4; ++c)
#pragma unroll
        for (int r = 0; r < 4; ++r) {
          int row = rowbase + mf * 16 + 4 * g + r;
          dst[(size_t)row * HEADD + 16 * c + l15] = f2bf(acc[mf][c][r] * s);
        }
  }
}

// ---------------------------------------------------------------------------
// Kernel 2: causal flash attention. 2 waves/block, wave owns 16 q-rows.
// Swapped QK^T: S^T = mfma(K, Q^T) so lane's scores all belong to q = lane&15.
// P transposed to PV A-frag layout via small padded per-wave LDS buffer.
// V^T gives contiguous 16B PV B-frag loads.
// ---------------------------------------------------------------------------
__global__ __launch_bounds__(128) void attn_kernel(
    const u16* __restrict__ Kb, const u16* __restrict__ Qb, const u16* __restrict__ Vt,
    float* __restrict__ out) {
  __shared__ __align__(16) u16 plds[2][16 * 40];  // per-wave P tile [16q][32k], pad->40
  int lane = threadIdx.x & 63;
  int wv = threadIdx.x >> 6;
  int l15 = lane & 15, g = lane >> 4;
  int b = blockIdx.y;
  int qt = 63 - (int)blockIdx.x;          // heavy tiles first
  int qbase = qt * 32 + wv * 16;          // within batch

  const u16* Qp = Qb + ((size_t)b * LSEQ + qbase) * HEADD;
  const u16* Kp = Kb + (size_t)b * LSEQ * HEADD;
  const u16* Vp = Vt + (size_t)b * HEADD * LSEQ;

  bf16x8 qf[2];
#pragma unroll
  for (int ds = 0; ds < 2; ++ds)
    qf[ds] = *(const bf16x8*)(Qp + (size_t)l15 * HEADD + 32 * ds + 8 * g);

  f32x4 acc[4] = {};        // [c]: reg r -> q-row qbase+4g+r, col d=16c+l15
  float m = -1e30f, lsum = 0.f;
  int q_abs = qbase + l15;
  int ntiles = (qbase + 47) >> 5;

  for (int t = 0; t < ntiles; ++t) {
    int kbase = t * 32;
    f32x4 sacc[2] = {};     // [f]: key = kbase+16f+4g+r, q = qbase+l15
#pragma unroll
    for (int f = 0; f < 2; ++f)
#pragma unroll
      for (int ds = 0; ds < 2; ++ds) {
        bf16x8 kf = *(const bf16x8*)(Kp + (size_t)(kbase + 16 * f + l15) * HEADD + 32 * ds + 8 * g);
        sacc[f] = __builtin_amdgcn_mfma_f32_16x16x32_bf16(kf, qf[ds], sacc[f], 0, 0, 0);
      }

    // causal mask + row-max (row == this lane's q)
    float sv[2][4];
    float tmax = -1e30f;
#pragma unroll
    for (int f = 0; f < 2; ++f)
#pragma unroll
      for (int r = 0; r < 4; ++r) {
        int key = kbase + 16 * f + 4 * g + r;
        float s = (key <= q_abs) ? sacc[f][r] : -1e30f;
        sv[f][r] = s;
        tmax = fmaxf(tmax, s);
      }
    tmax = fmaxf(tmax, __shfl_xor(tmax, 16));
    tmax = fmaxf(tmax, __shfl_xor(tmax, 32));
    float mnew = fmaxf(m, tmax);
    float al = __expf(m - mnew);
    float pv[2][4];
    float rs = 0.f;
#pragma unroll
    for (int f = 0; f < 2; ++f)
#pragma unroll
      for (int r = 0; r < 4; ++r) {
        pv[f][r] = __expf(sv[f][r] - mnew);
        rs += pv[f][r];
      }
    rs += __shfl_xor(rs, 16);
    rs += __shfl_xor(rs, 32);
    lsum = lsum * al + rs;
    m = mnew;

    // rescale O accumulator: row 4g+r's factor lives at lane (4g+r) (group 0 copy)
    float alr[4];
#pragma unroll
    for (int r = 0; r < 4; ++r) alr[r] = __shfl(al, 4 * g + r);
#pragma unroll
    for (int c = 0; c < 4; ++c)
#pragma unroll
      for (int r = 0; r < 4; ++r) acc[c][r] *= alr[r];

    // P -> LDS in PV A-frag layout: P[q=l15][key 16f+4g + r]
#pragma unroll
    for (int f = 0; f < 2; ++f) {
      ushort4 pk;
      pk.x = f2bf(pv[f][0]); pk.y = f2bf(pv[f][1]);
      pk.z = f2bf(pv[f][2]); pk.w = f2bf(pv[f][3]);
      *(ushort4*)&plds[wv][l15 * 40 + 16 * f + 4 * g] = pk;
    }
    bf16x8 ap = *(const bf16x8*)&plds[wv][l15 * 40 + 8 * g];

    // PV: B-frag = V[kbase+8g+j][16c+l15] = Vt[16c+l15][kbase+8g+j] (contiguous)
#pragma unroll
    for (int c = 0; c < 4; ++c) {
      bf16x8 vf = *(const bf16x8*)(Vp + (size_t)(16 * c + l15) * LSEQ + kbase + 8 * g);
      acc[c] = __builtin_amdgcn_mfma_f32_16x16x32_bf16(ap, vf, acc[c], 0, 0, 0);
    }
  }

  // normalize and store fp32 output
  float li[4];
#pragma unroll
  for (int r = 0; r < 4; ++r) {
    float lv = __shfl(lsum, 4 * g + r);
    li[r] = 1.0f / lv;
  }
#pragma unroll
  for (int c = 0; c < 4; ++c)
#pragma unroll
    for (int r = 0; r < 4; ++r)
      out[((size_t)b * LSEQ + qbase + 4 * g + r) * HEADD + 16 * c + l15] = acc[c][r] * li[r];
}

// ---------------------------------------------------------------------------
extern "C" void kernel_launch(void* const* d_in, const int* in_sizes, int n_in,
                              void* d_out, int out_size, void* d_ws, size_t ws_size,
                              hipStream_t stream) {
  const float* idx_k = (const float*)d_in[0];
  const float* idx_q = (const float*)d_in[1];
  const float* idx_v = (const float*)d_in[2];
  // d_in[3] = msk : causal mask is applied analytically, never read
  const float* Wk = (const float*)d_in[4];
  const float* Wq = (const float*)d_in[5];
  const float* Wv = (const float*)d_in[6];
  float* out = (float*)d_out;

  char* ws = (char*)d_ws;
  const size_t WT_BYTES = (size_t)3 * HEADD * DMODEL * 2;        // 384 KB
  const size_t MAT_BYTES = (size_t)NBATCH * LSEQ * HEADD * 2;    // 2 MB each
  u16* wt = (u16*)ws;
  u16* Kb = (u16*)(ws + WT_BYTES);
  u16* Qb = (u16*)(ws + WT_BYTES + MAT_BYTES);
  u16* Vt = (u16*)(ws + WT_BYTES + 2 * MAT_BYTES);

  hipLaunchKernelGGL(wt_kernel, dim3(64, 3), dim3(256), 0, stream, Wk, Wq, Wv, wt);
  hipLaunchKernelGGL(proj_kernel, dim3(128, 3), dim3(256), 0, stream,
                     idx_k, idx_q, idx_v, wt, Kb, Qb, Vt);
  hipLaunchKernelGGL(attn_kernel, dim3(64, NBATCH), dim3(128), 0, stream, Kb, Qb, Vt, out);
}